// Round 6
// baseline (584.393 us; speedup 1.0000x reference)
//
#include <hip/hip_runtime.h>
#include <math.h>

#define BATCH 256
#define CH 512
#define SE_CH 32
#define HW 1024            // 32*32 floats per plane
#define HALF 256           // channels per workgroup-unit (half a batch = 1 MB)
#define NBLK 256           // one block per CU -> all co-resident, no deadlock
#define ROUNDS 2           // 512 units / 256 blocks

typedef float f32x4 __attribute__((ext_vector_type(4)));

// One-pass SE block: x is read once into registers, means/FC computed with a
// 32-float cross-workgroup exchange (the two halves of a batch), result
// applied from registers and streamed out. HBM traffic = 512 MB in + 512 MB out.
__global__ __launch_bounds__(1024, 1) void se_onepass(
        const float* __restrict__ x,
        float* __restrict__ out,
        const float* __restrict__ fc1_w,   // [SE_CH][CH]
        const float* __restrict__ fc1_b,   // [SE_CH]
        const float* __restrict__ fc2_w,   // [2*CH][SE_CH]
        const float* __restrict__ fc2_b,   // [2*CH]
        float* __restrict__ yacc,          // [BATCH][SE_CH]  (zeroed per call)
        int* __restrict__ flags) {         // [BATCH]         (zeroed per call)
    const int t = threadIdx.x;
    const int wave = t >> 6;       // 0..15
    const int lane = t & 63;

    __shared__ float m[HALF];      // plane means of this half
    __shared__ float sev[SE_CH];   // se vector after relu
    __shared__ float sc[HALF];     // sigmoid(scale) per local channel
    __shared__ float bo[HALF];     // bias per local channel

    for (int r = 0; r < ROUNDS; ++r) {
        const int unit = (int)blockIdx.x + NBLK * r;   // 0..511
        const int b = unit >> 1;                       // batch element
        const int h = unit & 1;                        // which half of channels
        const size_t base = ((size_t)b * CH + (size_t)h * HALF) * HW;
        const f32x4* xb = (const f32x4*)(x + base);

        // ---- load 1 MB into registers: wave w owns planes w*16..w*16+15,
        //      lane holds f32x4 slots {lane, lane+64, lane+128, lane+192} ----
        f32x4 d[16][4];
#pragma unroll
        for (int p = 0; p < 16; ++p) {
#pragma unroll
            for (int j = 0; j < 4; ++j)
                d[p][j] = __builtin_nontemporal_load(
                    &xb[(size_t)(wave * 16 + p) * 256 + j * 64 + lane]);
        }

        // ---- per-plane means (64-lane xor reduce, 16 independent chains) ----
#pragma unroll
        for (int p = 0; p < 16; ++p) {
            f32x4 s4 = (d[p][0] + d[p][1]) + (d[p][2] + d[p][3]);
            float s = (s4.x + s4.y) + (s4.z + s4.w);
#pragma unroll
            for (int off = 32; off; off >>= 1)
                s += __shfl_xor(s, off, 64);
            if (lane == 0)
                m[wave * 16 + p] = s * (1.0f / 1024.0f);
        }
        __syncthreads();

        // ---- partial FC1 over this half's channels; exchange via atomicAdd ----
        {
            const int o = wave * 2 + (lane >> 5);      // 0..31, 32 lanes each
            const int cl0 = lane & 31;
            const float* wr = fc1_w + (size_t)o * CH + (size_t)h * HALF;
            float acc = 0.0f;
#pragma unroll
            for (int k = 0; k < 8; ++k)
                acc = fmaf(wr[cl0 + 32 * k], m[cl0 + 32 * k], acc);
#pragma unroll
            for (int off = 16; off; off >>= 1)
                acc += __shfl_xor(acc, off, 64);
            if (cl0 == 0)
                __hip_atomic_fetch_add(&yacc[b * SE_CH + o], acc,
                                       __ATOMIC_RELAXED, __HIP_MEMORY_SCOPE_AGENT);
        }
        __syncthreads();   // every wave's atomic has drained (vmcnt0 at barrier)

        if (t == 0) {
            __hip_atomic_fetch_add(&flags[b], 1,
                                   __ATOMIC_RELEASE, __HIP_MEMORY_SCOPE_AGENT);
            // partner block is guaranteed resident (1 block/CU, grid==CU count)
            while (__hip_atomic_load(&flags[b], __ATOMIC_ACQUIRE,
                                     __HIP_MEMORY_SCOPE_AGENT) < 2)
                __builtin_amdgcn_s_sleep(2);
        }
        __syncthreads();

        // ---- finish FC1 (bias+relu), then FC2 for this half's channels ----
        if (t < SE_CH) {
            float y = __hip_atomic_load(&yacc[b * SE_CH + t],
                                        __ATOMIC_RELAXED, __HIP_MEMORY_SCOPE_AGENT);
            sev[t] = fmaxf(y + fc1_b[t], 0.0f);
        }
        __syncthreads();

        if (t < 2 * HALF) {
            const int cl = t & (HALF - 1);
            const int row = (t < HALF) ? (h * HALF + cl) : (CH + h * HALF + cl);
            const float* wr = fc2_w + (size_t)row * SE_CH;
            float acc = fc2_b[row];
#pragma unroll
            for (int k = 0; k < SE_CH; ++k)
                acc = fmaf(wr[k], sev[k], acc);
            if (t < HALF)
                sc[cl] = 1.0f / (1.0f + expf(-acc));
            else
                bo[cl] = acc;
        }
        __syncthreads();

        // ---- apply from registers, nontemporal store ----
        f32x4* ob = (f32x4*)(out + base);
#pragma unroll
        for (int p = 0; p < 16; ++p) {
            const float s = sc[wave * 16 + p];
            const float bb = bo[wave * 16 + p];
#pragma unroll
            for (int j = 0; j < 4; ++j) {
                f32x4 v = d[p][j];
                f32x4 rr;
                rr.x = fmaf(v.x, s, bb);
                rr.y = fmaf(v.y, s, bb);
                rr.z = fmaf(v.z, s, bb);
                rr.w = fmaf(v.w, s, bb);
                __builtin_nontemporal_store(
                    rr, &ob[(size_t)(wave * 16 + p) * 256 + j * 64 + lane]);
            }
        }
        // no barrier needed here: next round only touches m before its first
        // __syncthreads, and m is not read during apply (sc/bo only).
    }
}

extern "C" void kernel_launch(void* const* d_in, const int* in_sizes, int n_in,
                              void* d_out, int out_size, void* d_ws, size_t ws_size,
                              hipStream_t stream) {
    const float* x     = (const float*)d_in[0];
    const float* fc1_w = (const float*)d_in[1];
    const float* fc1_b = (const float*)d_in[2];
    const float* fc2_w = (const float*)d_in[3];
    const float* fc2_b = (const float*)d_in[4];
    float* out = (float*)d_out;

    float* yacc = (float*)d_ws;                          // BATCH*SE_CH f32 = 32 KB
    int* flags  = (int*)((char*)d_ws + BATCH * SE_CH * sizeof(float));  // 1 KB

    // zero the exchange buffers every call (graph-capture legal)
    hipMemsetAsync(d_ws, 0, BATCH * SE_CH * sizeof(float) + BATCH * sizeof(int),
                   stream);

    se_onepass<<<NBLK, 1024, 0, stream>>>(x, out, fc1_w, fc1_b, fc2_w, fc2_b,
                                          yacc, flags);
}